// Round 2
// baseline (407.389 us; speedup 1.0000x reference)
//
#include <hip/hip_runtime.h>

#define BB 4
#define LS 160
#define LW 128
#define DD 768
#define NSPANS 996
#define NZv 64
#define NPAIR 4096
#define HID 128

// ---------- helpers ----------

__device__ inline void span_decode(int s, int& st, int& en, int& w) {
  int ww = 1, base = 0;
  while (ww < 8 && s >= base + (129 - ww)) { base += 129 - ww; ++ww; }
  st = s - base; en = st + ww - 1; w = ww;
}

__device__ inline int bucket17(int v) {
  // searchsorted(BINS, v, 'right') - 1, BINS={0,1,...,10,15,20,25,30,50,80}
  const int BINSv[17] = {0,1,2,3,4,5,6,7,8,9,10,15,20,25,30,50,80};
  int r = 0;
#pragma unroll
  for (int k = 1; k < 17; ++k) r += (v >= BINSv[k]) ? 1 : 0;
  return r;
}

// ---------- kernel 1: gathered subword->word feats ----------
// f[b,i,d] = (1/wlen[b,i]) * sum_t mask[b, fss[b,i], t] * lh[b,t,d]
__global__ __launch_bounds__(256) void feats_kernel(
    const float* __restrict__ mask, const float* __restrict__ lh,
    const int* __restrict__ fss, const float* __restrict__ wlen,
    float* __restrict__ f) {
  int b = blockIdx.y, ct = blockIdx.x;  // ct: 0..5 col-tile of 128
  __shared__ float ms[128][17];
  __shared__ float lhs[16][129];
  __shared__ int   fssl[128];
  __shared__ float wll[128];
  int tid = threadIdx.x;
  if (tid < 128) { fssl[tid] = fss[b * LW + tid]; wll[tid] = wlen[b * LW + tid]; }
  __syncthreads();
  int tr = tid >> 4, tc = tid & 15;
  float acc[8][8] = {{0.f}};
  for (int t0 = 0; t0 < LS; t0 += 16) {
#pragma unroll
    for (int u = 0; u < 8; ++u) {
      int idx = tid + u * 256; int r = idx >> 4, c = idx & 15;
      ms[r][c] = mask[(b * LS + fssl[r]) * LS + t0 + c];
    }
#pragma unroll
    for (int u = 0; u < 8; ++u) {
      int idx = tid + u * 256; int r = idx >> 7, c = idx & 127;
      lhs[r][c] = lh[(b * LS + t0 + r) * DD + ct * 128 + c];
    }
    __syncthreads();
#pragma unroll
    for (int kk = 0; kk < 16; ++kk) {
      float av[8], bv[8];
#pragma unroll
      for (int i = 0; i < 8; ++i) av[i] = ms[tr + 16 * i][kk];
#pragma unroll
      for (int j = 0; j < 8; ++j) bv[j] = lhs[kk][tc + 16 * j];
#pragma unroll
      for (int i = 0; i < 8; ++i)
#pragma unroll
        for (int j = 0; j < 8; ++j) acc[i][j] += av[i] * bv[j];
    }
    __syncthreads();
  }
#pragma unroll
  for (int i = 0; i < 8; ++i) {
    int r = tr + 16 * i; float wl = wll[r];
#pragma unroll
    for (int j = 0; j < 8; ++j) {
      int c = tc + 16 * j;
      f[(b * LW + r) * DD + ct * 128 + c] = acc[i][j] / wl;
    }
  }
}

// ---------- kernel 2: small embedding-projection tables ----------
// S_W(+sb1), T_W, O_W, R17, D30(+pb1)
__global__ __launch_bounds__(256) void smalltab_kernel(
    const float* __restrict__ width_table, const float* __restrict__ rel_table,
    const float* __restrict__ dep_table, const float* __restrict__ sW1,
    const float* __restrict__ pW1, const float* __restrict__ sb1,
    const float* __restrict__ pb1, float* __restrict__ tabs) {
  int bt = blockIdx.x;
  const float *src, *W, *bias; int rows; float* out;
  switch (bt) {
    case 0: src = width_table; W = sW1 + 1664 * HID; bias = sb1;    rows = 17; out = tabs;        break;
    case 1: src = width_table; W = pW1 + 1664 * HID; bias = nullptr; rows = 17; out = tabs + 2176; break;
    case 2: src = width_table; W = pW1 + 3392 * HID; bias = nullptr; rows = 17; out = tabs + 4352; break;
    case 3: src = rel_table;   W = pW1 + 3456 * HID; bias = nullptr; rows = 17; out = tabs + 6528; break;
    default:src = dep_table;   W = pW1 + 3520 * HID; bias = pb1;    rows = 30; out = tabs + 8704; break;
  }
  for (int e = threadIdx.x; e < rows * HID; e += 256) {
    int r = e >> 7, c = e & 127;
    float acc = 0.f;
#pragma unroll 8
    for (int k = 0; k < 64; ++k) acc += src[r * 64 + k] * W[k * HID + c];
    out[e] = acc + (bias ? bias[c] : 0.f);
  }
}

// ---------- kernel 3: per-word projections S_A,S_B,T_A,T_B,O_A,O_B ----------
__global__ __launch_bounds__(256) void proj_kernel(
    const float* __restrict__ f, const int* __restrict__ pos_id,
    const float* __restrict__ pos_table, const float* __restrict__ sW1,
    const float* __restrict__ pW1, float* __restrict__ out) {
  int b = blockIdx.y, bt = blockIdx.x;
  const float* Wb; int f_off, p_off;
  switch (bt) {
    case 0: Wb = sW1; f_off = 0;    p_off = 1536; break;  // S_A
    case 1: Wb = sW1; f_off = 768;  p_off = 1600; break;  // S_B
    case 2: Wb = pW1; f_off = 0;    p_off = 1536; break;  // T_A
    case 3: Wb = pW1; f_off = 768;  p_off = 1600; break;  // T_B
    case 4: Wb = pW1; f_off = 1728; p_off = 3264; break;  // O_A
    default:Wb = pW1; f_off = 2496; p_off = 3328; break;  // O_B
  }
  float* op = out + (size_t)(bt * BB + b) * LW * HID;
  __shared__ float xs[128][17];
  __shared__ float wsh[16][129];
  __shared__ int pid[128];
  int tid = threadIdx.x;
  if (tid < 128) pid[tid] = pos_id[b * LW + tid];
  __syncthreads();
  int tr = tid >> 4, tc = tid & 15;
  float acc[8][8] = {{0.f}};
  // K phase 1: word feats (768)
  for (int k0 = 0; k0 < DD; k0 += 16) {
#pragma unroll
    for (int u = 0; u < 8; ++u) {
      int idx = tid + u * 256; int r = idx >> 4, c = idx & 15;
      xs[r][c] = f[(b * LW + r) * DD + k0 + c];
    }
#pragma unroll
    for (int u = 0; u < 8; ++u) {
      int idx = tid + u * 256; int r = idx >> 7, c = idx & 127;
      wsh[r][c] = Wb[(f_off + k0 + r) * HID + c];
    }
    __syncthreads();
#pragma unroll
    for (int kk = 0; kk < 16; ++kk) {
      float av[8], bv[8];
#pragma unroll
      for (int i = 0; i < 8; ++i) av[i] = xs[tr + 16 * i][kk];
#pragma unroll
      for (int j = 0; j < 8; ++j) bv[j] = wsh[kk][tc + 16 * j];
#pragma unroll
      for (int i = 0; i < 8; ++i)
#pragma unroll
        for (int j = 0; j < 8; ++j) acc[i][j] += av[i] * bv[j];
    }
    __syncthreads();
  }
  // K phase 2: pos embedding (64)
  for (int k0 = 0; k0 < 64; k0 += 16) {
#pragma unroll
    for (int u = 0; u < 8; ++u) {
      int idx = tid + u * 256; int r = idx >> 4, c = idx & 15;
      xs[r][c] = pos_table[pid[r] * 64 + k0 + c];
    }
#pragma unroll
    for (int u = 0; u < 8; ++u) {
      int idx = tid + u * 256; int r = idx >> 7, c = idx & 127;
      wsh[r][c] = Wb[(p_off + k0 + r) * HID + c];
    }
    __syncthreads();
#pragma unroll
    for (int kk = 0; kk < 16; ++kk) {
      float av[8], bv[8];
#pragma unroll
      for (int i = 0; i < 8; ++i) av[i] = xs[tr + 16 * i][kk];
#pragma unroll
      for (int j = 0; j < 8; ++j) bv[j] = wsh[kk][tc + 16 * j];
#pragma unroll
      for (int i = 0; i < 8; ++i)
#pragma unroll
        for (int j = 0; j < 8; ++j) acc[i][j] += av[i] * bv[j];
    }
    __syncthreads();
  }
#pragma unroll
  for (int i = 0; i < 8; ++i)
#pragma unroll
    for (int j = 0; j < 8; ++j)
      op[(tr + 16 * i) * HID + tc + 16 * j] = acc[i][j];
}

// ---------- kernel 4: span FFNN + write span_prob ----------
__global__ __launch_bounds__(256) void span_kernel(
    const float* __restrict__ proj, const float* __restrict__ tabs,
    const float* __restrict__ sW2, const float* __restrict__ sb2,
    const float* __restrict__ sW3, const float* __restrict__ sb3,
    float* __restrict__ out) {
  int b = blockIdx.y, s0 = blockIdx.x * 64;
  int cnt = min(64, NSPANS - s0);
  __shared__ float h[64][129];
  __shared__ float wsh[16][129];
  __shared__ int stl[64], enl[64], wdl[64];
  int tid = threadIdx.x;
  if (tid < 64 && tid < cnt) {
    int st, en, w; span_decode(s0 + tid, st, en, w);
    stl[tid] = st; enl[tid] = en; wdl[tid] = w;
  }
  __syncthreads();
  const float* SA = proj + (size_t)(0 * BB + b) * LW * HID;
  const float* SBp = proj + (size_t)(1 * BB + b) * LW * HID;
  const float* SW = tabs;  // includes sb1
#pragma unroll
  for (int u = 0; u < 32; ++u) {
    int e = tid + u * 256; int r = e >> 7, c = e & 127;
    float v = 0.f;
    if (r < cnt)
      v = SA[stl[r] * HID + c] + SBp[enl[r] * HID + c] + SW[wdl[r] * HID + c];
    h[r][c] = fmaxf(v, 0.f);
  }
  __syncthreads();
  // h2 = relu(h1 @ sW2 + sb2)
  int tr = tid >> 5, tc = tid & 31;
  float acc[8][4] = {{0.f}};
  for (int k0 = 0; k0 < HID; k0 += 16) {
#pragma unroll
    for (int u = 0; u < 8; ++u) {
      int idx = tid + u * 256; int r = idx >> 7, c = idx & 127;
      wsh[r][c] = sW2[(k0 + r) * HID + c];
    }
    __syncthreads();
#pragma unroll
    for (int kk = 0; kk < 16; ++kk) {
      float av[8], bv[4];
#pragma unroll
      for (int i = 0; i < 8; ++i) av[i] = h[tr + 8 * i][k0 + kk];
#pragma unroll
      for (int j = 0; j < 4; ++j) bv[j] = wsh[kk][tc + 32 * j];
#pragma unroll
      for (int i = 0; i < 8; ++i)
#pragma unroll
        for (int j = 0; j < 4; ++j) acc[i][j] += av[i] * bv[j];
    }
    __syncthreads();
  }
#pragma unroll
  for (int i = 0; i < 8; ++i)
#pragma unroll
    for (int j = 0; j < 4; ++j)
      h[tr + 8 * i][tc + 32 * j] = fmaxf(acc[i][j] + sb2[tc + 32 * j], 0.f);
  __syncthreads();
  // out3 = h2 @ sW3 + sb3
  if (tid < 192) {
    int sl = tid / 3, oc = tid - sl * 3;
    if (sl < cnt) {
      float a = sb3[oc];
#pragma unroll 16
      for (int k = 0; k < HID; ++k) a += h[sl][k] * sW3[k * 3 + oc];
      out[(b * NSPANS + s0 + sl) * 3 + oc] = a;
    }
  }
}

// ---------- kernel 5: exact stable top-64 (value desc, tie -> lower index) ----------
__global__ __launch_bounds__(256) void topk_kernel(
    const float* __restrict__ out, int* __restrict__ tix, int* __restrict__ oix) {
  int b = blockIdx.y; int ch = blockIdx.x + 1;
  __shared__ float sc[NSPANS];
  __shared__ float rv[256];
  __shared__ int ri[256];
  int tid = threadIdx.x;
  for (int e = tid; e < NSPANS; e += 256) sc[e] = out[(b * NSPANS + e) * 3 + ch];
  __syncthreads();
  int* dst = (ch == 1 ? tix : oix) + b * NZv;
  for (int k = 0; k < NZv; ++k) {
    float bv = -INFINITY; int bi = NSPANS;
    for (int e = tid; e < NSPANS; e += 256) {
      float v = sc[e];
      if (v > bv || (v == bv && e < bi)) { bv = v; bi = e; }
    }
    rv[tid] = bv; ri[tid] = bi;
    __syncthreads();
    for (int off = 128; off > 0; off >>= 1) {
      if (tid < off) {
        float v2 = rv[tid + off]; int i2 = ri[tid + off];
        if (v2 > rv[tid] || (v2 == rv[tid] && i2 < ri[tid])) { rv[tid] = v2; ri[tid] = i2; }
      }
      __syncthreads();
    }
    if (tid == 0) { dst[k] = ri[0]; sc[ri[0]] = -INFINITY; }
    __syncthreads();
  }
}

// ---------- kernel 6: pair FFNN + write pair_prob ----------
__global__ __launch_bounds__(256) void pair_kernel(
    const float* __restrict__ proj, const float* __restrict__ tabs,
    const int* __restrict__ tix, const int* __restrict__ oix,
    const int* __restrict__ dep_dis, const float* __restrict__ pW2,
    const float* __restrict__ pb2, const float* __restrict__ pW3,
    const float* __restrict__ pb3, float* __restrict__ out) {
  int b = blockIdx.y, p0 = blockIdx.x * 64;
  __shared__ float h[64][129];
  __shared__ float wsh[16][129];
  __shared__ int mTA[64], mTB[64], mOA[64], mOB[64], mTW[64], mOW[64], mR[64], mD[64];
  int tid = threadIdx.x;
  // phase 0: pair metadata, 4 threads per pair
  {
    int m = tid >> 2, sub = tid & 3;
    int p = p0 + m;
    int ti = tix[b * NZv + (p >> 6)];
    int oi = oix[b * NZv + (p & 63)];
    int a, bb2, wt, c, d, wo;
    span_decode(ti, a, bb2, wt);
    span_decode(oi, c, d, wo);
    int mn = 0x7FFFFFFF;
    const int* dp = dep_dis + b * LW * LW;
    for (int x = a; x <= bb2; ++x)
      for (int y = c + sub; y <= d; y += 4)
        mn = min(mn, dp[x * LW + y]);
    mn = min(mn, __shfl_xor(mn, 1));
    mn = min(mn, __shfl_xor(mn, 2));
    if (sub == 0) {
      int rel = min(abs(bb2 - c), abs(a - d));
      mTA[m] = ((2 * BB + b) * LW + a)   * HID;
      mTB[m] = ((3 * BB + b) * LW + bb2) * HID;
      mOA[m] = ((4 * BB + b) * LW + c)   * HID;
      mOB[m] = ((5 * BB + b) * LW + d)   * HID;
      mTW[m] = 2176 + wt * HID;
      mOW[m] = 4352 + wo * HID;
      mR[m]  = 6528 + bucket17(rel) * HID;
      mD[m]  = 8704 + mn * HID;   // includes pb1
    }
  }
  __syncthreads();
  // phase 1: h1 = relu(sum of 8 gathered vectors)
#pragma unroll
  for (int u = 0; u < 32; ++u) {
    int e = tid + u * 256; int r = e >> 7, c = e & 127;
    float v = proj[mTA[r] + c] + proj[mTB[r] + c] + proj[mOA[r] + c] +
              proj[mOB[r] + c] + tabs[mTW[r] + c] + tabs[mOW[r] + c] +
              tabs[mR[r] + c] + tabs[mD[r] + c];
    h[r][c] = fmaxf(v, 0.f);
  }
  __syncthreads();
  // phase 2: h2 = relu(h1 @ pW2 + pb2)
  int tr = tid >> 5, tc = tid & 31;
  float acc[8][4] = {{0.f}};
  for (int k0 = 0; k0 < HID; k0 += 16) {
#pragma unroll
    for (int u = 0; u < 8; ++u) {
      int idx = tid + u * 256; int r = idx >> 7, c = idx & 127;
      wsh[r][c] = pW2[(k0 + r) * HID + c];
    }
    __syncthreads();
#pragma unroll
    for (int kk = 0; kk < 16; ++kk) {
      float av[8], bv[4];
#pragma unroll
      for (int i = 0; i < 8; ++i) av[i] = h[tr + 8 * i][k0 + kk];
#pragma unroll
      for (int j = 0; j < 4; ++j) bv[j] = wsh[kk][tc + 32 * j];
#pragma unroll
      for (int i = 0; i < 8; ++i)
#pragma unroll
        for (int j = 0; j < 4; ++j) acc[i][j] += av[i] * bv[j];
    }
    __syncthreads();
  }
#pragma unroll
  for (int i = 0; i < 8; ++i)
#pragma unroll
    for (int j = 0; j < 4; ++j)
      h[tr + 8 * i][tc + 32 * j] = fmaxf(acc[i][j] + pb2[tc + 32 * j], 0.f);
  __syncthreads();
  // phase 3: out4 = h2 @ pW3 + pb3
  {
    int sl = tid >> 2, oc = tid & 3;
    float a = pb3[oc];
#pragma unroll 16
    for (int k = 0; k < HID; ++k) a += h[sl][k] * pW3[k * 4 + oc];
    out[BB * NSPANS * 3 + (b * NPAIR + p0 + sl) * 4 + oc] = a;
  }
}

extern "C" void kernel_launch(void* const* d_in, const int* in_sizes, int n_in,
                              void* d_out, int out_size, void* d_ws, size_t ws_size,
                              hipStream_t stream) {
  const float* last_hidden = (const float*)d_in[0];
  const float* mask        = (const float*)d_in[1];
  const float* word_len    = (const float*)d_in[2];
  const float* pos_table   = (const float*)d_in[3];
  const float* width_table = (const float*)d_in[4];
  const float* rel_table   = (const float*)d_in[5];
  const float* dep_table   = (const float*)d_in[6];
  const float* sW1 = (const float*)d_in[7];
  const float* sb1 = (const float*)d_in[8];
  const float* sW2 = (const float*)d_in[9];
  const float* sb2 = (const float*)d_in[10];
  const float* sW3 = (const float*)d_in[11];
  const float* sb3 = (const float*)d_in[12];
  const float* pW1 = (const float*)d_in[13];
  const float* pb1 = (const float*)d_in[14];
  const float* pW2 = (const float*)d_in[15];
  const float* pb2 = (const float*)d_in[16];
  const float* pW3 = (const float*)d_in[17];
  const float* pb3 = (const float*)d_in[18];
  const int* fss     = (const int*)d_in[19];
  const int* pos_id  = (const int*)d_in[20];
  const int* dep_dis = (const int*)d_in[21];

  float* ws   = (float*)d_ws;
  float* f    = ws;             // B*LW*D             = 393216 floats
  float* proj = ws + 393216;    // 6*B*LW*HID         = 393216 floats
  float* tabs = ws + 786432;    // 2176*4 + 3840      = 12544 floats
  int*   tix  = (int*)(ws + 798976);  // B*64
  int*   oix  = tix + 256;
  float* out  = (float*)d_out;

  feats_kernel<<<dim3(6, BB), 256, 0, stream>>>(mask, last_hidden, fss, word_len, f);
  smalltab_kernel<<<5, 256, 0, stream>>>(width_table, rel_table, dep_table,
                                         sW1, pW1, sb1, pb1, tabs);
  proj_kernel<<<dim3(6, BB), 256, 0, stream>>>(f, pos_id, pos_table, sW1, pW1, proj);
  span_kernel<<<dim3(16, BB), 256, 0, stream>>>(proj, tabs, sW2, sb2, sW3, sb3, out);
  topk_kernel<<<dim3(2, BB), 256, 0, stream>>>(out, tix, oix);
  pair_kernel<<<dim3(64, BB), 256, 0, stream>>>(proj, tabs, tix, oix, dep_dis,
                                                pW2, pb2, pW3, pb3, out);
}

// Round 3
// 267.061 us; speedup vs baseline: 1.5255x; 1.5255x over previous
//
#include <hip/hip_runtime.h>

#define BB 4
#define LS 160
#define LW 128
#define DD 768
#define NSPANS 996
#define NZv 64
#define NPAIR 4096
#define HID 128
#define XLD 832          // X row stride: 768 feats + 64 pos
#define PROJ_N 393216    // 6*BB*LW*HID

// ---------- helpers ----------

__device__ inline void span_decode(int s, int& st, int& en, int& w) {
  int ww = 1, base = 0;
  while (ww < 8 && s >= base + (129 - ww)) { base += 129 - ww; ++ww; }
  st = s - base; en = st + ww - 1; w = ww;
}

__device__ inline int bucket17(int v) {
  const int BINSv[17] = {0,1,2,3,4,5,6,7,8,9,10,15,20,25,30,50,80};
  int r = 0;
#pragma unroll
  for (int k = 1; k < 17; ++k) r += (v >= BINSv[k]) ? 1 : 0;
  return r;
}

// ---------- kernel 1: gathered subword->word feats -> X[:, 0:768] ----------
// grid (12, 8), block 256. X[row, c] = (1/wlen[row]) * sum_t mask[b, fss[row], t] * lh[b,t,c]
__global__ __launch_bounds__(256) void feats_kernel(
    const float* __restrict__ mask, const float* __restrict__ lh,
    const int* __restrict__ fss, const float* __restrict__ wlen,
    float* __restrict__ X) {
  int nt = blockIdx.x, mt = blockIdx.y;
  int b = mt >> 1;
  int row0 = mt * 64, c0 = nt * 64;
  __shared__ float as[16][68];   // [k][row]
  __shared__ float bs[16][68];   // [k][col]
  __shared__ int fssl[64];
  __shared__ float wll[64];
  int tid = threadIdx.x;
  if (tid < 64) { fssl[tid] = fss[row0 + tid]; wll[tid] = wlen[row0 + tid]; }
  __syncthreads();
  int rg = tid >> 4, tc = tid & 15;
  float acc[4][4] = {{0.f}};
  for (int k0 = 0; k0 < LS; k0 += 16) {
    {
      int r = tid >> 2, kb = (tid & 3) * 4;
      float4 mv = *(const float4*)(mask + (size_t)(b * LS + fssl[r]) * LS + k0 + kb);
      as[kb + 0][r] = mv.x; as[kb + 1][r] = mv.y;
      as[kb + 2][r] = mv.z; as[kb + 3][r] = mv.w;
    }
    {
      int c = tid & 63, kq = tid >> 6;
#pragma unroll
      for (int q = 0; q < 4; ++q) {
        int kk = kq * 4 + q;
        bs[kk][c] = lh[(size_t)(b * LS + k0 + kk) * DD + c0 + c];
      }
    }
    __syncthreads();
#pragma unroll
    for (int kk = 0; kk < 16; ++kk) {
      float av[4], bv[4];
#pragma unroll
      for (int i = 0; i < 4; ++i) av[i] = as[kk][rg * 4 + i];
#pragma unroll
      for (int j = 0; j < 4; ++j) bv[j] = bs[kk][tc * 4 + j];
#pragma unroll
      for (int i = 0; i < 4; ++i)
#pragma unroll
        for (int j = 0; j < 4; ++j) acc[i][j] += av[i] * bv[j];
    }
    __syncthreads();
  }
#pragma unroll
  for (int i = 0; i < 4; ++i) {
    int r = rg * 4 + i;
    float wl = wll[r];
    float4 v = make_float4(acc[i][0] / wl, acc[i][1] / wl, acc[i][2] / wl, acc[i][3] / wl);
    *(float4*)(X + (size_t)(row0 + r) * XLD + c0 + tc * 4) = v;
  }
}

// ---------- kernel 1b: pos embedding -> X[:, 768:832] ----------
__global__ __launch_bounds__(256) void posfill_kernel(
    const int* __restrict__ pos_id, const float* __restrict__ pos_table,
    float* __restrict__ X) {
  int idx = blockIdx.x * 256 + threadIdx.x;   // 512*64 = 32768
  int row = idx >> 6, c = idx & 63;
  X[(size_t)row * XLD + 768 + c] = pos_table[pos_id[row] * 64 + c];
}

// ---------- kernel 2: small embedding-projection tables ----------
__global__ __launch_bounds__(256) void smalltab_kernel(
    const float* __restrict__ width_table, const float* __restrict__ rel_table,
    const float* __restrict__ dep_table, const float* __restrict__ sW1,
    const float* __restrict__ pW1, const float* __restrict__ sb1,
    const float* __restrict__ pb1, float* __restrict__ tabs) {
  int bt = blockIdx.x;
  const float *src, *W, *bias; int rows; float* out;
  switch (bt) {
    case 0: src = width_table; W = sW1 + 1664 * HID; bias = sb1;    rows = 17; out = tabs;        break;
    case 1: src = width_table; W = pW1 + 1664 * HID; bias = nullptr; rows = 17; out = tabs + 2176; break;
    case 2: src = width_table; W = pW1 + 3392 * HID; bias = nullptr; rows = 17; out = tabs + 4352; break;
    case 3: src = rel_table;   W = pW1 + 3456 * HID; bias = nullptr; rows = 17; out = tabs + 6528; break;
    default:src = dep_table;   W = pW1 + 3520 * HID; bias = pb1;    rows = 30; out = tabs + 8704; break;
  }
  for (int e = threadIdx.x; e < rows * HID; e += 256) {
    int r = e >> 7, c = e & 127;
    float acc = 0.f;
#pragma unroll 8
    for (int k = 0; k < 64; ++k) acc += src[r * 64 + k] * W[k * HID + c];
    out[e] = acc + (bias ? bias[c] : 0.f);
  }
}

// ---------- kernel 3: split-K GEMM: proj partials = X @ W6 ----------
// grid (12, 8, 2), block 256. nt -> (g = nt>>1, half), mt -> 64 rows, ks -> K chunk of 416
__global__ __launch_bounds__(256) void proj_gemm(
    const float* __restrict__ X, const float* __restrict__ sW1,
    const float* __restrict__ pW1, float* __restrict__ part) {
  int nt = blockIdx.x, mt = blockIdx.y, ks = blockIdx.z;
  const int f_offs[6] = {0, 768, 0, 768, 1728, 2496};
  const int p_offs[6] = {1536, 1600, 1536, 1600, 3264, 3328};
  int g = nt >> 1;
  const float* Wb = (g < 2) ? sW1 : pW1;
  int f_off = f_offs[g], p_off = p_offs[g];
  int c0 = (nt & 1) * 64;
  int row0 = mt * 64;
  int kbase = ks * 416;
  __shared__ float as[16][68];   // [k][row]
  __shared__ float bs[16][68];   // [k][col]
  int tid = threadIdx.x;
  int rg = tid >> 4, tc = tid & 15;
  float acc[4][4] = {{0.f}};
  for (int k0 = 0; k0 < 416; k0 += 16) {
    {
      int r = tid >> 2, kb = (tid & 3) * 4;
      float4 xv = *(const float4*)(X + (size_t)(row0 + r) * XLD + kbase + k0 + kb);
      as[kb + 0][r] = xv.x; as[kb + 1][r] = xv.y;
      as[kb + 2][r] = xv.z; as[kb + 3][r] = xv.w;
    }
    {
      int c = tid & 63, kq = tid >> 6;
#pragma unroll
      for (int q = 0; q < 4; ++q) {
        int kk = kq * 4 + q;
        int kg = kbase + k0 + kk;
        int wr = (kg < 768) ? (f_off + kg) : (p_off + kg - 768);
        bs[kk][c] = Wb[(size_t)wr * HID + c0 + c];
      }
    }
    __syncthreads();
#pragma unroll
    for (int kk = 0; kk < 16; ++kk) {
      float av[4], bv[4];
#pragma unroll
      for (int i = 0; i < 4; ++i) av[i] = as[kk][rg * 4 + i];
#pragma unroll
      for (int j = 0; j < 4; ++j) bv[j] = bs[kk][tc * 4 + j];
#pragma unroll
      for (int i = 0; i < 4; ++i)
#pragma unroll
        for (int j = 0; j < 4; ++j) acc[i][j] += av[i] * bv[j];
    }
    __syncthreads();
  }
#pragma unroll
  for (int i = 0; i < 4; ++i) {
    int row = row0 + rg * 4 + i;
    int bb = row >> 7, iloc = row & 127;
    float* dst = part + (size_t)ks * PROJ_N +
                 ((size_t)(g * BB + bb) * LW + iloc) * HID + c0 + tc * 4;
    *(float4*)dst = make_float4(acc[i][0], acc[i][1], acc[i][2], acc[i][3]);
  }
}

// ---------- kernel 3b: reduce the two K-split partials ----------
__global__ __launch_bounds__(256) void reduce_kernel(
    const float* __restrict__ part, float* __restrict__ proj) {
  int idx = blockIdx.x * 256 + threadIdx.x;   // PROJ_N/4 = 98304 float4s
  float4 a = ((const float4*)part)[idx];
  float4 b = ((const float4*)(part + PROJ_N))[idx];
  ((float4*)proj)[idx] = make_float4(a.x + b.x, a.y + b.y, a.z + b.z, a.w + b.w);
}

// ---------- kernel 4: span FFNN + write span_prob ----------
__global__ __launch_bounds__(256) void span_kernel(
    const float* __restrict__ proj, const float* __restrict__ tabs,
    const float* __restrict__ sW2, const float* __restrict__ sb2,
    const float* __restrict__ sW3, const float* __restrict__ sb3,
    float* __restrict__ out) {
  int b = blockIdx.y, s0 = blockIdx.x * 64;
  int cnt = min(64, NSPANS - s0);
  __shared__ float h[64][129];
  __shared__ float wsh[16][129];
  __shared__ int stl[64], enl[64], wdl[64];
  int tid = threadIdx.x;
  if (tid < 64 && tid < cnt) {
    int st, en, w; span_decode(s0 + tid, st, en, w);
    stl[tid] = st; enl[tid] = en; wdl[tid] = w;
  }
  __syncthreads();
  const float* SA = proj + (size_t)(0 * BB + b) * LW * HID;
  const float* SBp = proj + (size_t)(1 * BB + b) * LW * HID;
  const float* SW = tabs;  // includes sb1
#pragma unroll
  for (int u = 0; u < 32; ++u) {
    int e = tid + u * 256; int r = e >> 7, c = e & 127;
    float v = 0.f;
    if (r < cnt)
      v = SA[stl[r] * HID + c] + SBp[enl[r] * HID + c] + SW[wdl[r] * HID + c];
    h[r][c] = fmaxf(v, 0.f);
  }
  __syncthreads();
  int tr = tid >> 5, tc = tid & 31;
  float acc[8][4] = {{0.f}};
  for (int k0 = 0; k0 < HID; k0 += 16) {
#pragma unroll
    for (int u = 0; u < 8; ++u) {
      int idx = tid + u * 256; int r = idx >> 7, c = idx & 127;
      wsh[r][c] = sW2[(k0 + r) * HID + c];
    }
    __syncthreads();
#pragma unroll
    for (int kk = 0; kk < 16; ++kk) {
      float av[8], bv[4];
#pragma unroll
      for (int i = 0; i < 8; ++i) av[i] = h[tr + 8 * i][k0 + kk];
#pragma unroll
      for (int j = 0; j < 4; ++j) bv[j] = wsh[kk][tc + 32 * j];
#pragma unroll
      for (int i = 0; i < 8; ++i)
#pragma unroll
        for (int j = 0; j < 4; ++j) acc[i][j] += av[i] * bv[j];
    }
    __syncthreads();
  }
#pragma unroll
  for (int i = 0; i < 8; ++i)
#pragma unroll
    for (int j = 0; j < 4; ++j)
      h[tr + 8 * i][tc + 32 * j] = fmaxf(acc[i][j] + sb2[tc + 32 * j], 0.f);
  __syncthreads();
  if (tid < 192) {
    int sl = tid / 3, oc = tid - sl * 3;
    if (sl < cnt) {
      float a = sb3[oc];
#pragma unroll 16
      for (int k = 0; k < HID; ++k) a += h[sl][k] * sW3[k * 3 + oc];
      out[(b * NSPANS + s0 + sl) * 3 + oc] = a;
    }
  }
}

// ---------- kernel 5: single-wave top-64, exact tie rule, no barriers ----------
__global__ __launch_bounds__(64) void topk_kernel(
    const float* __restrict__ out, int* __restrict__ tix, int* __restrict__ oix) {
  int b = blockIdx.y, ch = blockIdx.x + 1;
  int lane = threadIdx.x;
  float v[16];
#pragma unroll
  for (int j = 0; j < 16; ++j) {
    int e = lane + 64 * j;
    v[j] = (e < NSPANS) ? out[(b * NSPANS + e) * 3 + ch] : -INFINITY;
  }
  int* dst = (ch == 1 ? tix : oix) + b * NZv;
  for (int k = 0; k < NZv; ++k) {
    float bv = -INFINITY; int bj = 0;
#pragma unroll
    for (int j = 0; j < 16; ++j)
      if (v[j] > bv) { bv = v[j]; bj = j; }   // idx = lane+64j ascending in j
    int bidx = lane + 64 * bj;
#pragma unroll
    for (int off = 1; off < 64; off <<= 1) {
      float ov = __shfl_xor(bv, off);
      int oi = __shfl_xor(bidx, off);
      if (ov > bv || (ov == bv && oi < bidx)) { bv = ov; bidx = oi; }
    }
    if (lane == 0) dst[k] = bidx;
    int wl = bidx & 63, wj = bidx >> 6;
#pragma unroll
    for (int j = 0; j < 16; ++j)
      if (lane == wl && j == wj) v[j] = -INFINITY;
  }
}

// ---------- kernel 6: pair FFNN + write pair_prob ----------
__global__ __launch_bounds__(256) void pair_kernel(
    const float* __restrict__ proj, const float* __restrict__ tabs,
    const int* __restrict__ tix, const int* __restrict__ oix,
    const int* __restrict__ dep_dis, const float* __restrict__ pW2,
    const float* __restrict__ pb2, const float* __restrict__ pW3,
    const float* __restrict__ pb3, float* __restrict__ out) {
  int b = blockIdx.y, p0 = blockIdx.x * 64;
  __shared__ float h[64][129];
  __shared__ float wsh[16][129];
  __shared__ int mTA[64], mTB[64], mOA[64], mOB[64], mTW[64], mOW[64], mR[64], mD[64];
  int tid = threadIdx.x;
  {
    int m = tid >> 2, sub = tid & 3;
    int p = p0 + m;
    int ti = tix[b * NZv + (p >> 6)];
    int oi = oix[b * NZv + (p & 63)];
    int a, bb2, wt, c, d, wo;
    span_decode(ti, a, bb2, wt);
    span_decode(oi, c, d, wo);
    int mn = 0x7FFFFFFF;
    const int* dp = dep_dis + b * LW * LW;
    for (int x = a; x <= bb2; ++x)
      for (int y = c + sub; y <= d; y += 4)
        mn = min(mn, dp[x * LW + y]);
    mn = min(mn, __shfl_xor(mn, 1));
    mn = min(mn, __shfl_xor(mn, 2));
    if (sub == 0) {
      int rel = min(abs(bb2 - c), abs(a - d));
      mTA[m] = ((2 * BB + b) * LW + a)   * HID;
      mTB[m] = ((3 * BB + b) * LW + bb2) * HID;
      mOA[m] = ((4 * BB + b) * LW + c)   * HID;
      mOB[m] = ((5 * BB + b) * LW + d)   * HID;
      mTW[m] = 2176 + wt * HID;
      mOW[m] = 4352 + wo * HID;
      mR[m]  = 6528 + bucket17(rel) * HID;
      mD[m]  = 8704 + mn * HID;   // includes pb1
    }
  }
  __syncthreads();
#pragma unroll
  for (int u = 0; u < 32; ++u) {
    int e = tid + u * 256; int r = e >> 7, c = e & 127;
    float v = proj[mTA[r] + c] + proj[mTB[r] + c] + proj[mOA[r] + c] +
              proj[mOB[r] + c] + tabs[mTW[r] + c] + tabs[mOW[r] + c] +
              tabs[mR[r] + c] + tabs[mD[r] + c];
    h[r][c] = fmaxf(v, 0.f);
  }
  __syncthreads();
  int tr = tid >> 5, tc = tid & 31;
  float acc[8][4] = {{0.f}};
  for (int k0 = 0; k0 < HID; k0 += 16) {
#pragma unroll
    for (int u = 0; u < 8; ++u) {
      int idx = tid + u * 256; int r = idx >> 7, c = idx & 127;
      wsh[r][c] = pW2[(k0 + r) * HID + c];
    }
    __syncthreads();
#pragma unroll
    for (int kk = 0; kk < 16; ++kk) {
      float av[8], bv[4];
#pragma unroll
      for (int i = 0; i < 8; ++i) av[i] = h[tr + 8 * i][k0 + kk];
#pragma unroll
      for (int j = 0; j < 4; ++j) bv[j] = wsh[kk][tc + 32 * j];
#pragma unroll
      for (int i = 0; i < 8; ++i)
#pragma unroll
        for (int j = 0; j < 4; ++j) acc[i][j] += av[i] * bv[j];
    }
    __syncthreads();
  }
#pragma unroll
  for (int i = 0; i < 8; ++i)
#pragma unroll
    for (int j = 0; j < 4; ++j)
      h[tr + 8 * i][tc + 32 * j] = fmaxf(acc[i][j] + pb2[tc + 32 * j], 0.f);
  __syncthreads();
  {
    int sl = tid >> 2, oc = tid & 3;
    float a = pb3[oc];
#pragma unroll 16
    for (int k = 0; k < HID; ++k) a += h[sl][k] * pW3[k * 4 + oc];
    out[BB * NSPANS * 3 + (b * NPAIR + p0 + sl) * 4 + oc] = a;
  }
}

extern "C" void kernel_launch(void* const* d_in, const int* in_sizes, int n_in,
                              void* d_out, int out_size, void* d_ws, size_t ws_size,
                              hipStream_t stream) {
  const float* last_hidden = (const float*)d_in[0];
  const float* mask        = (const float*)d_in[1];
  const float* word_len    = (const float*)d_in[2];
  const float* pos_table   = (const float*)d_in[3];
  const float* width_table = (const float*)d_in[4];
  const float* rel_table   = (const float*)d_in[5];
  const float* dep_table   = (const float*)d_in[6];
  const float* sW1 = (const float*)d_in[7];
  const float* sb1 = (const float*)d_in[8];
  const float* sW2 = (const float*)d_in[9];
  const float* sb2 = (const float*)d_in[10];
  const float* sW3 = (const float*)d_in[11];
  const float* sb3 = (const float*)d_in[12];
  const float* pW1 = (const float*)d_in[13];
  const float* pb1 = (const float*)d_in[14];
  const float* pW2 = (const float*)d_in[15];
  const float* pb2 = (const float*)d_in[16];
  const float* pW3 = (const float*)d_in[17];
  const float* pb3 = (const float*)d_in[18];
  const int* fss     = (const int*)d_in[19];
  const int* pos_id  = (const int*)d_in[20];
  const int* dep_dis = (const int*)d_in[21];

  float* ws   = (float*)d_ws;
  float* X    = ws;                       // 512*832       = 425984
  float* part = ws + 425984;              // 2*PROJ_N      = 786432
  float* proj = ws + 1212416;             // PROJ_N        = 393216
  float* tabs = ws + 1605632;             // 12544
  int*   tix  = (int*)(ws + 1618176);     // 256
  int*   oix  = tix + 256;                // 256
  float* out  = (float*)d_out;

  feats_kernel<<<dim3(12, 8), 256, 0, stream>>>(mask, last_hidden, fss, word_len, X);
  posfill_kernel<<<128, 256, 0, stream>>>(pos_id, pos_table, X);
  smalltab_kernel<<<5, 256, 0, stream>>>(width_table, rel_table, dep_table,
                                         sW1, pW1, sb1, pb1, tabs);
  proj_gemm<<<dim3(12, 8, 2), 256, 0, stream>>>(X, sW1, pW1, part);
  reduce_kernel<<<384, 256, 0, stream>>>(part, proj);
  span_kernel<<<dim3(16, BB), 256, 0, stream>>>(proj, tabs, sW2, sb2, sW3, sb3, out);
  topk_kernel<<<dim3(2, BB), 64, 0, stream>>>(out, tix, oix);
  pair_kernel<<<dim3(64, BB), 256, 0, stream>>>(proj, tabs, tix, oix, dep_dis,
                                                pW2, pb2, pW3, pb3, out);
}

// Round 4
// 245.318 us; speedup vs baseline: 1.6607x; 1.0886x over previous
//
#include <hip/hip_runtime.h>

#define BB 4
#define LS 160
#define LW 128
#define DD 768
#define NSPANS 996
#define NZv 64
#define NPAIR 4096
#define HID 128
#define XLD 832          // X row stride: 768 feats + 64 pos
#define PROJ_N 393216    // 6*BB*LW*HID

// ---------- helpers ----------

__device__ inline void span_decode(int s, int& st, int& en, int& w) {
  int ww = 1, base = 0;
  while (ww < 8 && s >= base + (129 - ww)) { base += 129 - ww; ++ww; }
  st = s - base; en = st + ww - 1; w = ww;
}

__device__ inline int bucket17(int v) {
  const int BINSv[17] = {0,1,2,3,4,5,6,7,8,9,10,15,20,25,30,50,80};
  int r = 0;
#pragma unroll
  for (int k = 1; k < 17; ++k) r += (v >= BINSv[k]) ? 1 : 0;
  return r;
}

// ---------- kernel 1: gathered subword->word feats -> X[:, 0:768] ----------
__global__ __launch_bounds__(256) void feats_kernel(
    const float* __restrict__ mask, const float* __restrict__ lh,
    const int* __restrict__ fss, const float* __restrict__ wlen,
    float* __restrict__ X) {
  int nt = blockIdx.x, mt = blockIdx.y;
  int b = mt >> 1;
  int row0 = mt * 64, c0 = nt * 64;
  __shared__ float as[16][68];   // [k][row]
  __shared__ float bs[16][68];   // [k][col]
  __shared__ int fssl[64];
  __shared__ float wll[64];
  int tid = threadIdx.x;
  if (tid < 64) { fssl[tid] = fss[row0 + tid]; wll[tid] = wlen[row0 + tid]; }
  __syncthreads();
  int rg = tid >> 4, tc = tid & 15;
  float acc[4][4] = {{0.f}};
  for (int k0 = 0; k0 < LS; k0 += 16) {
    {
      int r = tid >> 2, kb = (tid & 3) * 4;
      float4 mv = *(const float4*)(mask + (size_t)(b * LS + fssl[r]) * LS + k0 + kb);
      as[kb + 0][r] = mv.x; as[kb + 1][r] = mv.y;
      as[kb + 2][r] = mv.z; as[kb + 3][r] = mv.w;
    }
    {
      int c = tid & 63, kq = tid >> 6;
#pragma unroll
      for (int q = 0; q < 4; ++q) {
        int kk = kq * 4 + q;
        bs[kk][c] = lh[(size_t)(b * LS + k0 + kk) * DD + c0 + c];
      }
    }
    __syncthreads();
#pragma unroll
    for (int kk = 0; kk < 16; ++kk) {
      float av[4], bv[4];
#pragma unroll
      for (int i = 0; i < 4; ++i) av[i] = as[kk][rg * 4 + i];
#pragma unroll
      for (int j = 0; j < 4; ++j) bv[j] = bs[kk][tc * 4 + j];
#pragma unroll
      for (int i = 0; i < 4; ++i)
#pragma unroll
        for (int j = 0; j < 4; ++j) acc[i][j] += av[i] * bv[j];
    }
    __syncthreads();
  }
#pragma unroll
  for (int i = 0; i < 4; ++i) {
    int r = rg * 4 + i;
    float wl = wll[r];
    float4 v = make_float4(acc[i][0] / wl, acc[i][1] / wl, acc[i][2] / wl, acc[i][3] / wl);
    *(float4*)(X + (size_t)(row0 + r) * XLD + c0 + tc * 4) = v;
  }
}

// ---------- kernel 1b: pos embedding -> X[:, 768:832] ----------
__global__ __launch_bounds__(256) void posfill_kernel(
    const int* __restrict__ pos_id, const float* __restrict__ pos_table,
    float* __restrict__ X) {
  int idx = blockIdx.x * 256 + threadIdx.x;   // 512*64 = 32768
  int row = idx >> 6, c = idx & 63;
  X[(size_t)row * XLD + 768 + c] = pos_table[pos_id[row] * 64 + c];
}

// ---------- kernel 2: small embedding-projection tables ----------
__global__ __launch_bounds__(256) void smalltab_kernel(
    const float* __restrict__ width_table, const float* __restrict__ rel_table,
    const float* __restrict__ dep_table, const float* __restrict__ sW1,
    const float* __restrict__ pW1, const float* __restrict__ sb1,
    const float* __restrict__ pb1, float* __restrict__ tabs) {
  int bt = blockIdx.x;
  const float *src, *W, *bias; int rows; float* out;
  switch (bt) {
    case 0: src = width_table; W = sW1 + 1664 * HID; bias = sb1;    rows = 17; out = tabs;        break;
    case 1: src = width_table; W = pW1 + 1664 * HID; bias = nullptr; rows = 17; out = tabs + 2176; break;
    case 2: src = width_table; W = pW1 + 3392 * HID; bias = nullptr; rows = 17; out = tabs + 4352; break;
    case 3: src = rel_table;   W = pW1 + 3456 * HID; bias = nullptr; rows = 17; out = tabs + 6528; break;
    default:src = dep_table;   W = pW1 + 3520 * HID; bias = pb1;    rows = 30; out = tabs + 8704; break;
  }
  for (int e = threadIdx.x; e < rows * HID; e += 256) {
    int r = e >> 7, c = e & 127;
    float acc = 0.f;
#pragma unroll 8
    for (int k = 0; k < 64; ++k) acc += src[r * 64 + k] * W[k * HID + c];
    out[e] = acc + (bias ? bias[c] : 0.f);
  }
}

// ---------- kernel 3: split-K GEMM: proj partials = X @ W6 ----------
__global__ __launch_bounds__(256) void proj_gemm(
    const float* __restrict__ X, const float* __restrict__ sW1,
    const float* __restrict__ pW1, float* __restrict__ part) {
  int nt = blockIdx.x, mt = blockIdx.y, ks = blockIdx.z;
  const int f_offs[6] = {0, 768, 0, 768, 1728, 2496};
  const int p_offs[6] = {1536, 1600, 1536, 1600, 3264, 3328};
  int g = nt >> 1;
  const float* Wb = (g < 2) ? sW1 : pW1;
  int f_off = f_offs[g], p_off = p_offs[g];
  int c0 = (nt & 1) * 64;
  int row0 = mt * 64;
  int kbase = ks * 416;
  __shared__ float as[16][68];   // [k][row]
  __shared__ float bs[16][68];   // [k][col]
  int tid = threadIdx.x;
  int rg = tid >> 4, tc = tid & 15;
  float acc[4][4] = {{0.f}};
  for (int k0 = 0; k0 < 416; k0 += 16) {
    {
      int r = tid >> 2, kb = (tid & 3) * 4;
      float4 xv = *(const float4*)(X + (size_t)(row0 + r) * XLD + kbase + k0 + kb);
      as[kb + 0][r] = xv.x; as[kb + 1][r] = xv.y;
      as[kb + 2][r] = xv.z; as[kb + 3][r] = xv.w;
    }
    {
      int c = tid & 63, kq = tid >> 6;
#pragma unroll
      for (int q = 0; q < 4; ++q) {
        int kk = kq * 4 + q;
        int kg = kbase + k0 + kk;
        int wr = (kg < 768) ? (f_off + kg) : (p_off + kg - 768);
        bs[kk][c] = Wb[(size_t)wr * HID + c0 + c];
      }
    }
    __syncthreads();
#pragma unroll
    for (int kk = 0; kk < 16; ++kk) {
      float av[4], bv[4];
#pragma unroll
      for (int i = 0; i < 4; ++i) av[i] = as[kk][rg * 4 + i];
#pragma unroll
      for (int j = 0; j < 4; ++j) bv[j] = bs[kk][tc * 4 + j];
#pragma unroll
      for (int i = 0; i < 4; ++i)
#pragma unroll
        for (int j = 0; j < 4; ++j) acc[i][j] += av[i] * bv[j];
    }
    __syncthreads();
  }
#pragma unroll
  for (int i = 0; i < 4; ++i) {
    int row = row0 + rg * 4 + i;
    int bb = row >> 7, iloc = row & 127;
    float* dst = part + (size_t)ks * PROJ_N +
                 ((size_t)(g * BB + bb) * LW + iloc) * HID + c0 + tc * 4;
    *(float4*)dst = make_float4(acc[i][0], acc[i][1], acc[i][2], acc[i][3]);
  }
}

// ---------- kernel 3b: reduce the two K-split partials ----------
__global__ __launch_bounds__(256) void reduce_kernel(
    const float* __restrict__ part, float* __restrict__ proj) {
  int idx = blockIdx.x * 256 + threadIdx.x;   // PROJ_N/4 = 98304 float4s
  float4 a = ((const float4*)part)[idx];
  float4 b = ((const float4*)(part + PROJ_N))[idx];
  ((float4*)proj)[idx] = make_float4(a.x + b.x, a.y + b.y, a.z + b.z, a.w + b.w);
}

// ---------- kernel 4: span FFNN + write span_prob ----------
__global__ __launch_bounds__(256) void span_kernel(
    const float* __restrict__ proj, const float* __restrict__ tabs,
    const float* __restrict__ sW2, const float* __restrict__ sb2,
    const float* __restrict__ sW3, const float* __restrict__ sb3,
    float* __restrict__ out) {
  int b = blockIdx.y, s0 = blockIdx.x * 64;
  int cnt = min(64, NSPANS - s0);
  __shared__ float h[64][129];
  __shared__ float wsh[16][129];
  __shared__ int stl[64], enl[64], wdl[64];
  int tid = threadIdx.x;
  if (tid < 64 && tid < cnt) {
    int st, en, w; span_decode(s0 + tid, st, en, w);
    stl[tid] = st; enl[tid] = en; wdl[tid] = w;
  }
  __syncthreads();
  const float* SA = proj + (size_t)(0 * BB + b) * LW * HID;
  const float* SBp = proj + (size_t)(1 * BB + b) * LW * HID;
  const float* SW = tabs;  // includes sb1
#pragma unroll
  for (int u = 0; u < 32; ++u) {
    int e = tid + u * 256; int r = e >> 7, c = e & 127;
    float v = 0.f;
    if (r < cnt)
      v = SA[stl[r] * HID + c] + SBp[enl[r] * HID + c] + SW[wdl[r] * HID + c];
    h[r][c] = fmaxf(v, 0.f);
  }
  __syncthreads();
  int tr = tid >> 5, tc = tid & 31;
  float acc[8][4] = {{0.f}};
  for (int k0 = 0; k0 < HID; k0 += 16) {
#pragma unroll
    for (int u = 0; u < 8; ++u) {
      int idx = tid + u * 256; int r = idx >> 7, c = idx & 127;
      wsh[r][c] = sW2[(k0 + r) * HID + c];
    }
    __syncthreads();
#pragma unroll
    for (int kk = 0; kk < 16; ++kk) {
      float av[8], bv[4];
#pragma unroll
      for (int i = 0; i < 8; ++i) av[i] = h[tr + 8 * i][k0 + kk];
#pragma unroll
      for (int j = 0; j < 4; ++j) bv[j] = wsh[kk][tc + 32 * j];
#pragma unroll
      for (int i = 0; i < 8; ++i)
#pragma unroll
        for (int j = 0; j < 4; ++j) acc[i][j] += av[i] * bv[j];
    }
    __syncthreads();
  }
#pragma unroll
  for (int i = 0; i < 8; ++i)
#pragma unroll
    for (int j = 0; j < 4; ++j)
      h[tr + 8 * i][tc + 32 * j] = fmaxf(acc[i][j] + sb2[tc + 32 * j], 0.f);
  __syncthreads();
  if (tid < 192) {
    int sl = tid / 3, oc = tid - sl * 3;
    if (sl < cnt) {
      float a = sb3[oc];
#pragma unroll 16
      for (int k = 0; k < HID; ++k) a += h[sl][k] * sW3[k * 3 + oc];
      out[(b * NSPANS + s0 + sl) * 3 + oc] = a;
    }
  }
}

// ---------- kernel 5: bitonic-sort top-64 (exact lax.top_k order) ----------
// 1024 packed keys in LDS: (monotone(value) << 32) | (0xFFFFFFFF - index).
// Sort descending -> value desc, tie -> lower index first. Pad key = 0.
__global__ __launch_bounds__(256) void topk_kernel(
    const float* __restrict__ out, int* __restrict__ tix, int* __restrict__ oix) {
  int b = blockIdx.y, ch = blockIdx.x + 1;
  __shared__ unsigned long long keys[1024];
  int tid = threadIdx.x;
#pragma unroll
  for (int u = 0; u < 4; ++u) {
    int e = tid + u * 256;
    unsigned long long kk = 0ull;
    if (e < NSPANS) {
      unsigned int bits = __float_as_uint(out[(b * NSPANS + e) * 3 + ch]);
      unsigned int mv = (bits & 0x80000000u) ? ~bits : (bits | 0x80000000u);
      kk = ((unsigned long long)mv << 32) | (unsigned long long)(0xFFFFFFFFu - e);
    }
    keys[e] = kk;
  }
  __syncthreads();
  for (int k = 2; k <= 1024; k <<= 1) {
    for (int j = k >> 1; j > 0; j >>= 1) {
#pragma unroll
      for (int u = 0; u < 4; ++u) {
        int i = tid + u * 256;
        int l = i ^ j;
        if (l > i) {
          unsigned long long a = keys[i], c = keys[l];
          bool desc = ((i & k) == 0);
          if (desc ? (a < c) : (a > c)) { keys[i] = c; keys[l] = a; }
        }
      }
      __syncthreads();
    }
  }
  int* dst = (ch == 1 ? tix : oix) + b * NZv;
  if (tid < NZv) dst[tid] = (int)(0xFFFFFFFFu - (unsigned int)keys[tid]);
}

// ---------- kernel 6: pair FFNN + write pair_prob ----------
__global__ __launch_bounds__(256) void pair_kernel(
    const float* __restrict__ proj, const float* __restrict__ tabs,
    const int* __restrict__ tix, const int* __restrict__ oix,
    const int* __restrict__ dep_dis, const float* __restrict__ pW2,
    const float* __restrict__ pb2, const float* __restrict__ pW3,
    const float* __restrict__ pb3, float* __restrict__ out) {
  int b = blockIdx.y, p0 = blockIdx.x * 64;
  __shared__ float h[64][129];
  __shared__ float wsh[16][129];
  __shared__ int mTA[64], mTB[64], mOA[64], mOB[64], mTW[64], mOW[64], mR[64], mD[64];
  int tid = threadIdx.x;
  {
    int m = tid >> 2, sub = tid & 3;
    int p = p0 + m;
    int ti = tix[b * NZv + (p >> 6)];
    int oi = oix[b * NZv + (p & 63)];
    int a, bb2, wt, c, d, wo;
    span_decode(ti, a, bb2, wt);
    span_decode(oi, c, d, wo);
    int mn = 0x7FFFFFFF;
    const int* dp = dep_dis + b * LW * LW;
    for (int x = a; x <= bb2; ++x)
      for (int y = c + sub; y <= d; y += 4)
        mn = min(mn, dp[x * LW + y]);
    mn = min(mn, __shfl_xor(mn, 1));
    mn = min(mn, __shfl_xor(mn, 2));
    if (sub == 0) {
      int rel = min(abs(bb2 - c), abs(a - d));
      mTA[m] = ((2 * BB + b) * LW + a)   * HID;
      mTB[m] = ((3 * BB + b) * LW + bb2) * HID;
      mOA[m] = ((4 * BB + b) * LW + c)   * HID;
      mOB[m] = ((5 * BB + b) * LW + d)   * HID;
      mTW[m] = 2176 + wt * HID;
      mOW[m] = 4352 + wo * HID;
      mR[m]  = 6528 + bucket17(rel) * HID;
      mD[m]  = 8704 + mn * HID;   // includes pb1
    }
  }
  __syncthreads();
#pragma unroll
  for (int u = 0; u < 32; ++u) {
    int e = tid + u * 256; int r = e >> 7, c = e & 127;
    float v = proj[mTA[r] + c] + proj[mTB[r] + c] + proj[mOA[r] + c] +
              proj[mOB[r] + c] + tabs[mTW[r] + c] + tabs[mOW[r] + c] +
              tabs[mR[r] + c] + tabs[mD[r] + c];
    h[r][c] = fmaxf(v, 0.f);
  }
  __syncthreads();
  int tr = tid >> 5, tc = tid & 31;
  float acc[8][4] = {{0.f}};
  for (int k0 = 0; k0 < HID; k0 += 16) {
#pragma unroll
    for (int u = 0; u < 8; ++u) {
      int idx = tid + u * 256; int r = idx >> 7, c = idx & 127;
      wsh[r][c] = pW2[(k0 + r) * HID + c];
    }
    __syncthreads();
#pragma unroll
    for (int kk = 0; kk < 16; ++kk) {
      float av[8], bv[4];
#pragma unroll
      for (int i = 0; i < 8; ++i) av[i] = h[tr + 8 * i][k0 + kk];
#pragma unroll
      for (int j = 0; j < 4; ++j) bv[j] = wsh[kk][tc + 32 * j];
#pragma unroll
      for (int i = 0; i < 8; ++i)
#pragma unroll
        for (int j = 0; j < 4; ++j) acc[i][j] += av[i] * bv[j];
    }
    __syncthreads();
  }
#pragma unroll
  for (int i = 0; i < 8; ++i)
#pragma unroll
    for (int j = 0; j < 4; ++j)
      h[tr + 8 * i][tc + 32 * j] = fmaxf(acc[i][j] + pb2[tc + 32 * j], 0.f);
  __syncthreads();
  {
    int sl = tid >> 2, oc = tid & 3;
    float a = pb3[oc];
#pragma unroll 16
    for (int k = 0; k < HID; ++k) a += h[sl][k] * pW3[k * 4 + oc];
    out[BB * NSPANS * 3 + (b * NPAIR + p0 + sl) * 4 + oc] = a;
  }
}

extern "C" void kernel_launch(void* const* d_in, const int* in_sizes, int n_in,
                              void* d_out, int out_size, void* d_ws, size_t ws_size,
                              hipStream_t stream) {
  const float* last_hidden = (const float*)d_in[0];
  const float* mask        = (const float*)d_in[1];
  const float* word_len    = (const float*)d_in[2];
  const float* pos_table   = (const float*)d_in[3];
  const float* width_table = (const float*)d_in[4];
  const float* rel_table   = (const float*)d_in[5];
  const float* dep_table   = (const float*)d_in[6];
  const float* sW1 = (const float*)d_in[7];
  const float* sb1 = (const float*)d_in[8];
  const float* sW2 = (const float*)d_in[9];
  const float* sb2 = (const float*)d_in[10];
  const float* sW3 = (const float*)d_in[11];
  const float* sb3 = (const float*)d_in[12];
  const float* pW1 = (const float*)d_in[13];
  const float* pb1 = (const float*)d_in[14];
  const float* pW2 = (const float*)d_in[15];
  const float* pb2 = (const float*)d_in[16];
  const float* pW3 = (const float*)d_in[17];
  const float* pb3 = (const float*)d_in[18];
  const int* fss     = (const int*)d_in[19];
  const int* pos_id  = (const int*)d_in[20];
  const int* dep_dis = (const int*)d_in[21];

  float* ws   = (float*)d_ws;
  float* X    = ws;                       // 512*832       = 425984
  float* part = ws + 425984;              // 2*PROJ_N      = 786432
  float* proj = ws + 1212416;             // PROJ_N        = 393216
  float* tabs = ws + 1605632;             // 12544
  int*   tix  = (int*)(ws + 1618176);     // 256
  int*   oix  = tix + 256;                // 256
  float* out  = (float*)d_out;

  feats_kernel<<<dim3(12, 8), 256, 0, stream>>>(mask, last_hidden, fss, word_len, X);
  posfill_kernel<<<128, 256, 0, stream>>>(pos_id, pos_table, X);
  smalltab_kernel<<<5, 256, 0, stream>>>(width_table, rel_table, dep_table,
                                         sW1, pW1, sb1, pb1, tabs);
  proj_gemm<<<dim3(12, 8, 2), 256, 0, stream>>>(X, sW1, pW1, part);
  reduce_kernel<<<384, 256, 0, stream>>>(part, proj);
  span_kernel<<<dim3(16, BB), 256, 0, stream>>>(proj, tabs, sW2, sb2, sW3, sb3, out);
  topk_kernel<<<dim3(2, BB), 256, 0, stream>>>(out, tix, oix);
  pair_kernel<<<dim3(64, BB), 256, 0, stream>>>(proj, tabs, tix, oix, dep_dis,
                                                pW2, pb2, pW3, pb3, out);
}

// Round 5
// 222.143 us; speedup vs baseline: 1.8339x; 1.1043x over previous
//
#include <hip/hip_runtime.h>

#define BB 4
#define LS 160
#define LW 128
#define DD 768
#define NSPANS 996
#define NZv 64
#define NPAIR 4096
#define HID 128
#define XLD 832          // X row stride: 768 feats + 64 pos
#define PROJ_N 393216    // 6*BB*LW*HID

// ---------- helpers ----------

__device__ inline void span_decode(int s, int& st, int& en, int& w) {
  int ww = 1, base = 0;
  while (ww < 8 && s >= base + (129 - ww)) { base += 129 - ww; ++ww; }
  st = s - base; en = st + ww - 1; w = ww;
}

__device__ inline int bucket17(int v) {
  const int BINSv[17] = {0,1,2,3,4,5,6,7,8,9,10,15,20,25,30,50,80};
  int r = 0;
#pragma unroll
  for (int k = 1; k < 17; ++k) r += (v >= BINSv[k]) ? 1 : 0;
  return r;
}

// ---------- kernel 1: prep = feats (96 blocks) + posfill (8) + smalltab (5) ----------
__global__ __launch_bounds__(256) void prep_kernel(
    const float* __restrict__ mask, const float* __restrict__ lh,
    const int* __restrict__ fss, const float* __restrict__ wlen,
    const int* __restrict__ pos_id, const float* __restrict__ pos_table,
    const float* __restrict__ width_table, const float* __restrict__ rel_table,
    const float* __restrict__ dep_table, const float* __restrict__ sW1,
    const float* __restrict__ pW1, const float* __restrict__ sb1,
    const float* __restrict__ pb1, float* __restrict__ X,
    float* __restrict__ tabs) {
  int gid = blockIdx.x;
  int tid = threadIdx.x;
  if (gid < 96) {
    // ---- feats tile: X[:, 0:768] ----
    int nt = gid % 12, mt = gid / 12;
    int b = mt >> 1;
    int row0 = mt * 64, c0 = nt * 64;
    __shared__ float as[16][68];   // [k][row]
    __shared__ float bs[16][68];   // [k][col]
    __shared__ int fssl[64];
    __shared__ float wll[64];
    if (tid < 64) { fssl[tid] = fss[row0 + tid]; wll[tid] = wlen[row0 + tid]; }
    __syncthreads();
    int rg = tid >> 4, tc = tid & 15;
    float acc[4][4] = {{0.f}};
    for (int k0 = 0; k0 < LS; k0 += 16) {
      {
        int r = tid >> 2, kb = (tid & 3) * 4;
        float4 mv = *(const float4*)(mask + (size_t)(b * LS + fssl[r]) * LS + k0 + kb);
        as[kb + 0][r] = mv.x; as[kb + 1][r] = mv.y;
        as[kb + 2][r] = mv.z; as[kb + 3][r] = mv.w;
      }
      {
        int c = tid & 63, kq = tid >> 6;
#pragma unroll
        for (int q = 0; q < 4; ++q) {
          int kk = kq * 4 + q;
          bs[kk][c] = lh[(size_t)(b * LS + k0 + kk) * DD + c0 + c];
        }
      }
      __syncthreads();
#pragma unroll
      for (int kk = 0; kk < 16; ++kk) {
        float av[4], bv[4];
#pragma unroll
        for (int i = 0; i < 4; ++i) av[i] = as[kk][rg * 4 + i];
#pragma unroll
        for (int j = 0; j < 4; ++j) bv[j] = bs[kk][tc * 4 + j];
#pragma unroll
        for (int i = 0; i < 4; ++i)
#pragma unroll
          for (int j = 0; j < 4; ++j) acc[i][j] += av[i] * bv[j];
      }
      __syncthreads();
    }
#pragma unroll
    for (int i = 0; i < 4; ++i) {
      int r = rg * 4 + i;
      float wl = wll[r];
      float4 v = make_float4(acc[i][0] / wl, acc[i][1] / wl, acc[i][2] / wl, acc[i][3] / wl);
      *(float4*)(X + (size_t)(row0 + r) * XLD + c0 + tc * 4) = v;
    }
  } else if (gid < 104) {
    // ---- posfill: X[:, 768:832], 8 blocks x 256 threads x 16 elems ----
    int e0 = (gid - 96) * 4096 + tid * 16;
    int row = e0 >> 6, c0 = e0 & 63;
    const float* src = pos_table + pos_id[row] * 64 + c0;
    float* dst = X + (size_t)row * XLD + 768 + c0;
#pragma unroll
    for (int q = 0; q < 4; ++q)
      *(float4*)(dst + q * 4) = *(const float4*)(src + q * 4);
  } else {
    // ---- smalltab ----
    int bt = gid - 104;
    const float *src, *W, *bias; int rows; float* out;
    switch (bt) {
      case 0: src = width_table; W = sW1 + 1664 * HID; bias = sb1;    rows = 17; out = tabs;        break;
      case 1: src = width_table; W = pW1 + 1664 * HID; bias = nullptr; rows = 17; out = tabs + 2176; break;
      case 2: src = width_table; W = pW1 + 3392 * HID; bias = nullptr; rows = 17; out = tabs + 4352; break;
      case 3: src = rel_table;   W = pW1 + 3456 * HID; bias = nullptr; rows = 17; out = tabs + 6528; break;
      default:src = dep_table;   W = pW1 + 3520 * HID; bias = pb1;    rows = 30; out = tabs + 8704; break;
    }
    for (int e = tid; e < rows * HID; e += 256) {
      int r = e >> 7, c = e & 127;
      float acc = 0.f;
#pragma unroll 8
      for (int k = 0; k < 64; ++k) acc += src[r * 64 + k] * W[k * HID + c];
      out[e] = acc + (bias ? bias[c] : 0.f);
    }
  }
}

// ---------- kernel 2: split-K GEMM: part[ks] = X @ W6 (K chunk of 416) ----------
__global__ __launch_bounds__(256) void proj_gemm(
    const float* __restrict__ X, const float* __restrict__ sW1,
    const float* __restrict__ pW1, float* __restrict__ part) {
  int nt = blockIdx.x, mt = blockIdx.y, ks = blockIdx.z;
  const int f_offs[6] = {0, 768, 0, 768, 1728, 2496};
  const int p_offs[6] = {1536, 1600, 1536, 1600, 3264, 3328};
  int g = nt >> 1;
  const float* Wb = (g < 2) ? sW1 : pW1;
  int f_off = f_offs[g], p_off = p_offs[g];
  int c0 = (nt & 1) * 64;
  int row0 = mt * 64;
  int kbase = ks * 416;
  __shared__ float as[16][68];   // [k][row]
  __shared__ float bs[16][68];   // [k][col]
  int tid = threadIdx.x;
  int rg = tid >> 4, tc = tid & 15;
  float acc[4][4] = {{0.f}};
  for (int k0 = 0; k0 < 416; k0 += 16) {
    {
      int r = tid >> 2, kb = (tid & 3) * 4;
      float4 xv = *(const float4*)(X + (size_t)(row0 + r) * XLD + kbase + k0 + kb);
      as[kb + 0][r] = xv.x; as[kb + 1][r] = xv.y;
      as[kb + 2][r] = xv.z; as[kb + 3][r] = xv.w;
    }
    {
      int c = tid & 63, kq = tid >> 6;
#pragma unroll
      for (int q = 0; q < 4; ++q) {
        int kk = kq * 4 + q;
        int kg = kbase + k0 + kk;
        int wr = (kg < 768) ? (f_off + kg) : (p_off + kg - 768);
        bs[kk][c] = Wb[(size_t)wr * HID + c0 + c];
      }
    }
    __syncthreads();
#pragma unroll
    for (int kk = 0; kk < 16; ++kk) {
      float av[4], bv[4];
#pragma unroll
      for (int i = 0; i < 4; ++i) av[i] = as[kk][rg * 4 + i];
#pragma unroll
      for (int j = 0; j < 4; ++j) bv[j] = bs[kk][tc * 4 + j];
#pragma unroll
      for (int i = 0; i < 4; ++i)
#pragma unroll
        for (int j = 0; j < 4; ++j) acc[i][j] += av[i] * bv[j];
    }
    __syncthreads();
  }
#pragma unroll
  for (int i = 0; i < 4; ++i) {
    int row = row0 + rg * 4 + i;
    int bb = row >> 7, iloc = row & 127;
    float* dst = part + (size_t)ks * PROJ_N +
                 ((size_t)(g * BB + bb) * LW + iloc) * HID + c0 + tc * 4;
    *(float4*)dst = make_float4(acc[i][0], acc[i][1], acc[i][2], acc[i][3]);
  }
}

// ---------- kernel 3: span FFNN (32 spans/block) + write span_prob ----------
__global__ __launch_bounds__(256) void span_kernel(
    const float* __restrict__ part, const float* __restrict__ tabs,
    const float* __restrict__ sW2, const float* __restrict__ sb2,
    const float* __restrict__ sW3, const float* __restrict__ sb3,
    float* __restrict__ out) {
  int b = blockIdx.y, s0 = blockIdx.x * 32;
  int cnt = min(32, NSPANS - s0);
  __shared__ float h[32][129];
  __shared__ float wsh[16][132];
  __shared__ int stl[32], enl[32], wdl[32];
  int tid = threadIdx.x;
  if (tid < 32 && tid < cnt) {
    int st, en, w; span_decode(s0 + tid, st, en, w);
    stl[tid] = st; enl[tid] = en; wdl[tid] = w;
  }
  __syncthreads();
  const float* SA0 = part + (size_t)(0 * BB + b) * LW * HID;
  const float* SB0 = part + (size_t)(1 * BB + b) * LW * HID;
  const float* SA1 = SA0 + PROJ_N;
  const float* SB1 = SB0 + PROJ_N;
  const float* SW = tabs;  // includes sb1
#pragma unroll
  for (int u = 0; u < 16; ++u) {
    int e = tid + u * 256; int r = e >> 7, c = e & 127;
    float v = 0.f;
    if (r < cnt) {
      int sa = stl[r] * HID + c, sb = enl[r] * HID + c;
      v = ((SA0[sa] + SA1[sa]) + (SB0[sb] + SB1[sb])) + SW[wdl[r] * HID + c];
    }
    h[r][c] = fmaxf(v, 0.f);
  }
  __syncthreads();
  // h2 = relu(h1 @ sW2 + sb2): rows 32, cols 128; thread -> 4x4
  int rg = tid >> 5, tc = tid & 31;
  float acc[4][4] = {{0.f}};
  for (int k0 = 0; k0 < HID; k0 += 16) {
#pragma unroll
    for (int u = 0; u < 8; ++u) {
      int idx = tid + u * 256; int r = idx >> 7, c = idx & 127;
      wsh[r][c] = sW2[(k0 + r) * HID + c];
    }
    __syncthreads();
#pragma unroll
    for (int kk = 0; kk < 16; ++kk) {
      float av[4], bv[4];
#pragma unroll
      for (int i = 0; i < 4; ++i) av[i] = h[rg * 4 + i][k0 + kk];
#pragma unroll
      for (int j = 0; j < 4; ++j) bv[j] = wsh[kk][tc * 4 + j];
#pragma unroll
      for (int i = 0; i < 4; ++i)
#pragma unroll
        for (int j = 0; j < 4; ++j) acc[i][j] += av[i] * bv[j];
    }
    __syncthreads();
  }
  __shared__ float h2[32][129];
#pragma unroll
  for (int i = 0; i < 4; ++i)
#pragma unroll
    for (int j = 0; j < 4; ++j)
      h2[rg * 4 + i][tc * 4 + j] = fmaxf(acc[i][j] + sb2[tc * 4 + j], 0.f);
  __syncthreads();
  // out3 = h2 @ sW3 + sb3
  if (tid < 96) {
    int sl = tid / 3, oc = tid - sl * 3;
    if (sl < cnt) {
      float a = sb3[oc];
#pragma unroll 16
      for (int k = 0; k < HID; ++k) a += h2[sl][k] * sW3[k * 3 + oc];
      out[(b * NSPANS + s0 + sl) * 3 + oc] = a;
    }
  }
}

// ---------- kernel 4: bitonic-sort top-64 (exact lax.top_k order) ----------
__global__ __launch_bounds__(256) void topk_kernel(
    const float* __restrict__ out, int* __restrict__ tix, int* __restrict__ oix) {
  int b = blockIdx.y, ch = blockIdx.x + 1;
  __shared__ unsigned long long keys[1024];
  int tid = threadIdx.x;
#pragma unroll
  for (int u = 0; u < 4; ++u) {
    int e = tid + u * 256;
    unsigned long long kk = 0ull;
    if (e < NSPANS) {
      unsigned int bits = __float_as_uint(out[(b * NSPANS + e) * 3 + ch]);
      unsigned int mv = (bits & 0x80000000u) ? ~bits : (bits | 0x80000000u);
      kk = ((unsigned long long)mv << 32) | (unsigned long long)(0xFFFFFFFFu - e);
    }
    keys[e] = kk;
  }
  __syncthreads();
  for (int k = 2; k <= 1024; k <<= 1) {
    for (int j = k >> 1; j > 0; j >>= 1) {
#pragma unroll
      for (int u = 0; u < 4; ++u) {
        int i = tid + u * 256;
        int l = i ^ j;
        if (l > i) {
          unsigned long long a = keys[i], c = keys[l];
          bool desc = ((i & k) == 0);
          if (desc ? (a < c) : (a > c)) { keys[i] = c; keys[l] = a; }
        }
      }
      __syncthreads();
    }
  }
  int* dst = (ch == 1 ? tix : oix) + b * NZv;
  if (tid < NZv) dst[tid] = (int)(0xFFFFFFFFu - (unsigned int)keys[tid]);
}

// ---------- kernel 5: pair FFNN + write pair_prob ----------
__global__ __launch_bounds__(256) void pair_kernel(
    const float* __restrict__ part, const float* __restrict__ tabs,
    const int* __restrict__ tix, const int* __restrict__ oix,
    const int* __restrict__ dep_dis, const float* __restrict__ pW2,
    const float* __restrict__ pb2, const float* __restrict__ pW3,
    const float* __restrict__ pb3, float* __restrict__ out) {
  int b = blockIdx.y, p0 = blockIdx.x * 64;
  __shared__ float h[64][129];
  __shared__ float wsh[16][132];
  __shared__ int mTA[64], mTB[64], mOA[64], mOB[64], mTW[64], mOW[64], mR[64], mD[64];
  int tid = threadIdx.x;
  {
    int m = tid >> 2, sub = tid & 3;
    int p = p0 + m;
    int ti = tix[b * NZv + (p >> 6)];
    int oi = oix[b * NZv + (p & 63)];
    int a, bb2, wt, c, d, wo;
    span_decode(ti, a, bb2, wt);
    span_decode(oi, c, d, wo);
    int mn = 0x7FFFFFFF;
    const int* dp = dep_dis + b * LW * LW;
    for (int x = a; x <= bb2; ++x)
      for (int y = c + sub; y <= d; y += 4)
        mn = min(mn, dp[x * LW + y]);
    mn = min(mn, __shfl_xor(mn, 1));
    mn = min(mn, __shfl_xor(mn, 2));
    if (sub == 0) {
      int rel = min(abs(bb2 - c), abs(a - d));
      mTA[m] = ((2 * BB + b) * LW + a)   * HID;
      mTB[m] = ((3 * BB + b) * LW + bb2) * HID;
      mOA[m] = ((4 * BB + b) * LW + c)   * HID;
      mOB[m] = ((5 * BB + b) * LW + d)   * HID;
      mTW[m] = 2176 + wt * HID;
      mOW[m] = 4352 + wo * HID;
      mR[m]  = 6528 + bucket17(rel) * HID;
      mD[m]  = 8704 + mn * HID;   // includes pb1
    }
  }
  __syncthreads();
#pragma unroll
  for (int u = 0; u < 32; ++u) {
    int e = tid + u * 256; int r = e >> 7, c = e & 127;
    int ta = mTA[r] + c, tb = mTB[r] + c, oa = mOA[r] + c, ob = mOB[r] + c;
    float v = (part[ta] + part[ta + PROJ_N]) + (part[tb] + part[tb + PROJ_N]) +
              (part[oa] + part[oa + PROJ_N]) + (part[ob] + part[ob + PROJ_N]) +
              tabs[mTW[r] + c] + tabs[mOW[r] + c] +
              tabs[mR[r] + c] + tabs[mD[r] + c];
    h[r][c] = fmaxf(v, 0.f);
  }
  __syncthreads();
  int tr = tid >> 5, tc = tid & 31;
  float acc[8][4] = {{0.f}};
  for (int k0 = 0; k0 < HID; k0 += 16) {
#pragma unroll
    for (int u = 0; u < 8; ++u) {
      int idx = tid + u * 256; int r = idx >> 7, c = idx & 127;
      wsh[r][c] = pW2[(k0 + r) * HID + c];
    }
    __syncthreads();
#pragma unroll
    for (int kk = 0; kk < 16; ++kk) {
      float av[8], bv[4];
#pragma unroll
      for (int i = 0; i < 8; ++i) av[i] = h[tr + 8 * i][k0 + kk];
#pragma unroll
      for (int j = 0; j < 4; ++j) bv[j] = wsh[kk][tc + 32 * j];
#pragma unroll
      for (int i = 0; i < 8; ++i)
#pragma unroll
        for (int j = 0; j < 4; ++j) acc[i][j] += av[i] * bv[j];
    }
    __syncthreads();
  }
#pragma unroll
  for (int i = 0; i < 8; ++i)
#pragma unroll
    for (int j = 0; j < 4; ++j)
      h[tr + 8 * i][tc + 32 * j] = fmaxf(acc[i][j] + pb2[tc + 32 * j], 0.f);
  __syncthreads();
  {
    int sl = tid >> 2, oc = tid & 3;
    float a = pb3[oc];
#pragma unroll 16
    for (int k = 0; k < HID; ++k) a += h[sl][k] * pW3[k * 4 + oc];
    out[BB * NSPANS * 3 + (b * NPAIR + p0 + sl) * 4 + oc] = a;
  }
}

extern "C" void kernel_launch(void* const* d_in, const int* in_sizes, int n_in,
                              void* d_out, int out_size, void* d_ws, size_t ws_size,
                              hipStream_t stream) {
  const float* last_hidden = (const float*)d_in[0];
  const float* mask        = (const float*)d_in[1];
  const float* word_len    = (const float*)d_in[2];
  const float* pos_table   = (const float*)d_in[3];
  const float* width_table = (const float*)d_in[4];
  const float* rel_table   = (const float*)d_in[5];
  const float* dep_table   = (const float*)d_in[6];
  const float* sW1 = (const float*)d_in[7];
  const float* sb1 = (const float*)d_in[8];
  const float* sW2 = (const float*)d_in[9];
  const float* sb2 = (const float*)d_in[10];
  const float* sW3 = (const float*)d_in[11];
  const float* sb3 = (const float*)d_in[12];
  const float* pW1 = (const float*)d_in[13];
  const float* pb1 = (const float*)d_in[14];
  const float* pW2 = (const float*)d_in[15];
  const float* pb2 = (const float*)d_in[16];
  const float* pW3 = (const float*)d_in[17];
  const float* pb3 = (const float*)d_in[18];
  const int* fss     = (const int*)d_in[19];
  const int* pos_id  = (const int*)d_in[20];
  const int* dep_dis = (const int*)d_in[21];

  float* ws   = (float*)d_ws;
  float* X    = ws;                       // 512*832       = 425984
  float* part = ws + 425984;              // 2*PROJ_N      = 786432
  float* tabs = ws + 1212416;             // 12544
  int*   tix  = (int*)(ws + 1224960);     // 256
  int*   oix  = tix + 256;                // 256
  float* out  = (float*)d_out;

  prep_kernel<<<109, 256, 0, stream>>>(mask, last_hidden, fss, word_len,
                                       pos_id, pos_table, width_table, rel_table,
                                       dep_table, sW1, pW1, sb1, pb1, X, tabs);
  proj_gemm<<<dim3(12, 8, 2), 256, 0, stream>>>(X, sW1, pW1, part);
  span_kernel<<<dim3(32, BB), 256, 0, stream>>>(part, tabs, sW2, sb2, sW3, sb3, out);
  topk_kernel<<<dim3(2, BB), 256, 0, stream>>>(out, tix, oix);
  pair_kernel<<<dim3(64, BB), 256, 0, stream>>>(part, tabs, tix, oix, dep_dis,
                                                pW2, pb2, pW3, pb3, out);
}